// Round 8
// baseline (1279.686 us; speedup 1.0000x reference)
//
#include <hip/hip_runtime.h>
#include <stdint.h>

#define NN 100000
#define EE 625000
#define FF 128
#define HH 64
#define LL 6
#define TT 112

#define SCAN_CHUNK 2048
#define SCAN_NB ((NN + SCAN_CHUNK - 1) / SCAN_CHUNK)   // 49

typedef unsigned short u16;
typedef unsigned int u32;
typedef __attribute__((ext_vector_type(8))) short bf16x8;
typedef __attribute__((ext_vector_type(4))) float f32x4;

// ---- canonical bf16 weight block layout (u16 element offsets, all 8-aligned) ----
#define OFF_X    0u          // 800000   x [N,8]
#define OFF_TB   800000u     // 1600000  table [200000,8]
#define OFF_WO   2400000u    // 64       W_ohe
#define OFF_BO   2400064u    // 8        b_ohe
#define OFF_WE   2400072u    // 2048     W_enc [16,128]
#define OFF_BE   2402120u    // 128      b_enc
#define OFF_WED  2402248u    // 1024     W_edge [8,128]
#define OFF_BED  2403272u    // 128      b_edge
#define OFF_LW1  2403400u    // 57344    learner_W1 [7,128,64]
#define OFF_LB1  2460744u    // 448      learner_b1 [7,64]
#define OFF_LW2  2461192u    // 57344    learner_W2 [7,64,128]
#define OFF_LB2  2518536u    // 896      learner_b2 [7,128]
#define OFF_GW   2519432u    // 98304    gcn_W [6,128,128]
#define OFF_GB   2617736u    // 768      gcn_b [6,128]
#define OFF_GT   2618504u    // 6 (slot padded to 8) gcn_t
#define OFF_LG   2618512u    // 768      ln_gamma [6,128]
#define OFF_LB   2619280u    // 768      ln_beta [6,128]
#define OFF_WP   2620048u    // 14336    W_pred [128,112]
#define OFF_BP   2634384u    // 112      b_pred
#define CANON_N  2634496u

// ---------- bf16 helpers (OCP bf16 = upper 16 bits of f32, RNE pack) ----------
__device__ __forceinline__ float bf2f(u16 u) { return __uint_as_float(((u32)u) << 16); }
__device__ __forceinline__ float bflo(u32 u) { return __uint_as_float(u << 16); }
__device__ __forceinline__ float bfhi(u32 u) { return __uint_as_float(u & 0xffff0000u); }
__device__ __forceinline__ u16 f2bf(float f) {
    u32 u = __float_as_uint(f);
    u32 r = u + 0x7fffu + ((u >> 16) & 1u);   // RNE
    return (u16)(r >> 16);
}
__device__ __forceinline__ u32 pack2bf(float lo, float hi) {
    return ((u32)f2bf(hi) << 16) | (u32)f2bf(lo);
}
__device__ __forceinline__ uint4 pack8bf(const float* f) {
    uint4 r;
    r.x = pack2bf(f[0], f[1]); r.y = pack2bf(f[2], f[3]);
    r.z = pack2bf(f[4], f[5]); r.w = pack2bf(f[6], f[7]);
    return r;
}
__device__ __forceinline__ void unpack8bf(uint4 u, float* f) {
    f[0] = bflo(u.x); f[1] = bfhi(u.x); f[2] = bflo(u.y); f[3] = bfhi(u.y);
    f[4] = bflo(u.z); f[5] = bfhi(u.z); f[6] = bflo(u.w); f[7] = bfhi(u.w);
}
// dtype flag: gcn_t = ones(6). fp32: word0 = 0x3F800000 (low16==0); bf16: 0x3F803F80.
__device__ __forceinline__ bool is_f32(const u32* gt_raw) {
    return (gt_raw[0] & 0xFFFFu) == 0u;
}

// ---------- codebank load/store: fp32 (tier1) or bf16 (tier2) ----------
template<bool CB32>
__device__ __forceinline__ float4 cb_ld(const void* cb, size_t row, int v) {
    if (CB32) {
        return ((const float4*)cb)[row * 32 + v];
    } else {
        uint2 u = ((const uint2*)cb)[row * 32 + v];
        float4 r; r.x = bflo(u.x); r.y = bfhi(u.x); r.z = bflo(u.y); r.w = bfhi(u.y);
        return r;
    }
}
template<bool CB32>
__device__ __forceinline__ void cb_st(void* cb, size_t row, int v, float4 val) {
    if (CB32) {
        ((float4*)cb)[row * 32 + v] = val;
    } else {
        uint2 u; u.x = pack2bf(val.x, val.y); u.y = pack2bf(val.z, val.w);
        ((uint2*)cb)[row * 32 + v] = u;
    }
}

// ---------------- input canonicalization: any float input -> bf16 block ----------------
struct ConvPtrs { const void* p[19]; };

__global__ __launch_bounds__(256) void k_convw(ConvPtrs ps, u16* __restrict__ wc) {
    u32 idx = blockIdx.x * 256 + threadIdx.x;
    if (idx >= CANON_N) return;
    const u32 offs[19] = {OFF_X, OFF_TB, OFF_WO, OFF_BO, OFF_WE, OFF_BE, OFF_WED, OFF_BED,
                          OFF_LW1, OFF_LB1, OFF_LW2, OFF_LB2, OFF_GW, OFF_GB, OFF_GT,
                          OFF_LG, OFF_LB, OFF_WP, OFF_BP};
    int seg = 0;
#pragma unroll
    for (int s = 1; s < 19; s++) if (idx >= offs[s]) seg = s;
    u32 e = idx - offs[seg];
    u16 v;
    if (seg == 14 && e >= 6u) {
        v = 0;                                   // gcn_t slot padding
    } else {
        bool f32 = is_f32((const u32*)ps.p[14]);
        v = f32 ? f2bf(((const float*)ps.p[seg])[e]) : ((const u16*)ps.p[seg])[e];
    }
    wc[idx] = v;
}

// gcn_W transpose: wt[l][f][k] = W[l][k][f]  (B-frag = contiguous 8 bf16 from W^T rows)
__global__ __launch_bounds__(256) void k_twt(const u16* __restrict__ wc, u16* __restrict__ wt) {
    int idx = blockIdx.x * 256 + threadIdx.x;
    if (idx >= LL * FF * FF) return;
    int l = idx >> 14, r = (idx >> 7) & 127, c = idx & 127;
    wt[idx] = wc[OFF_GW + l * FF * FF + c * FF + r];
}

// weight transposes for MFMA kernels:
// w1t[ls][n][k] = W1[ls][k][n]; w2t[ls][n][k] = W2[ls][k][n];
// wet[n][k] = W_enc[k][n] (k<16; zero-pad to 32); wpt[n][k] = W_pred[k][n] (112 x 128)
__global__ __launch_bounds__(256) void k_twl(const u16* __restrict__ wc,
                                             u16* __restrict__ w1t, u16* __restrict__ w2t,
                                             u16* __restrict__ wet, u16* __restrict__ wpt) {
    int idx = blockIdx.x * 256 + threadIdx.x;
    const int HALF = 7 * FF * HH;                // 57344
    const int WETN = FF * 32;                    // 4096
    if (idx < HALF) {
        int ls = idx / (FF * HH), rem = idx % (FF * HH);
        int n = rem / FF, k = rem % FF;          // w1t row n (64 rows), col k (128)
        w1t[idx] = wc[OFF_LW1 + ls * FF * HH + k * HH + n];
    } else if (idx < 2 * HALF) {
        int j = idx - HALF;
        int ls = j / (FF * HH), rem = j % (FF * HH);
        int n = rem / HH, k = rem % HH;          // w2t row n (128 rows), col k (64)
        w2t[j] = wc[OFF_LW2 + ls * FF * HH + k * FF + n];
    } else if (idx < 2 * HALF + WETN) {
        int j = idx - 2 * HALF;
        int n = j >> 5, k = j & 31;              // wet row n (128 rows), col k (32)
        wet[j] = (k < 16) ? wc[OFF_WE + k * FF + n] : (u16)0;
    } else if (idx < 2 * HALF + WETN + TT * FF) {
        int j = idx - 2 * HALF - WETN;
        int n = j >> 7, k = j & 127;             // wpt row n (112 rows), col k (128)
        wpt[j] = wc[OFF_WP + k * TT + n];
    }
}

// ---------------- CSR build: histogram -> scan -> scatter ----------------
__global__ void k_hist(const int* __restrict__ dst, int* __restrict__ counts) {
    int e = blockIdx.x * 256 + threadIdx.x;
    if (e < EE) atomicAdd(&counts[dst[e]], 1);
}

__global__ void k_scan1(const int* __restrict__ counts, int* __restrict__ bsums) {
    __shared__ int red[256];
    int t = threadIdx.x;
    int base = blockIdx.x * SCAN_CHUNK + t * 8;
    int s = 0;
#pragma unroll
    for (int j = 0; j < 8; j++) { int i = base + j; s += (i < NN) ? counts[i] : 0; }
    red[t] = s; __syncthreads();
    for (int off = 128; off > 0; off >>= 1) {
        if (t < off) red[t] += red[t + off];
        __syncthreads();
    }
    if (t == 0) bsums[blockIdx.x] = red[0];
}

__global__ void k_scan2(int* __restrict__ bsums, int* __restrict__ row_ptr) {
    __shared__ int v[256];
    int t = threadIdx.x;
    int x = (t < SCAN_NB) ? bsums[t] : 0;
    v[t] = x; __syncthreads();
    for (int off = 1; off < 256; off <<= 1) {
        int add = (t >= off) ? v[t - off] : 0;
        __syncthreads();
        v[t] += add;
        __syncthreads();
    }
    if (t < SCAN_NB) bsums[t] = v[t] - x;   // exclusive
    if (t == 0) row_ptr[NN] = EE;
}

__global__ void k_scan3(int* counts_cursor, int* __restrict__ row_ptr,
                        const int* __restrict__ bsums) {
    __shared__ int red[256];
    int t = threadIdx.x;
    int base = blockIdx.x * SCAN_CHUNK + t * 8;
    int c[8]; int s = 0;
#pragma unroll
    for (int j = 0; j < 8; j++) { int i = base + j; c[j] = (i < NN) ? counts_cursor[i] : 0; s += c[j]; }
    red[t] = s; __syncthreads();
    int own = s;
    for (int off = 1; off < 256; off <<= 1) {
        int add = (t >= off) ? red[t - off] : 0;
        __syncthreads();
        red[t] += add;
        __syncthreads();
    }
    int off0 = bsums[blockIdx.x] + red[t] - own;
    int run = 0;
#pragma unroll
    for (int j = 0; j < 8; j++) {
        int i = base + j;
        if (i < NN) { row_ptr[i] = off0 + run; counts_cursor[i] = off0 + run; }
        run += c[j];
    }
}

// scatter src id + edge_attr (converted to bf16) into CSR order
__global__ void k_scatter(const int* __restrict__ src, const int* __restrict__ dst,
                          const void* __restrict__ edge_attr, const u32* __restrict__ gt_raw,
                          int* __restrict__ cursor, int* __restrict__ s_src,
                          u16* __restrict__ s_attr) {
    int e = blockIdx.x * 256 + threadIdx.x;
    if (e >= EE) return;
    int d = dst[e];
    int p = atomicAdd(&cursor[d], 1);
    s_src[p] = src[e];
    if (is_f32(gt_raw)) {
        const float4* ea = (const float4*)edge_attr;
        float4 lo = ea[(size_t)e * 2], hi = ea[(size_t)e * 2 + 1];
        float f[8] = {lo.x, lo.y, lo.z, lo.w, hi.x, hi.y, hi.z, hi.w};
        ((uint4*)s_attr)[p] = pack8bf(f);
    } else {
        ((uint4*)s_attr)[p] = ((const uint4*)edge_attr)[e];
    }
}

// ---------------- encoder via MFMA (R4 verified; R6: scratch union + 4-pass epilogue) ----------------
// zh/zl tiles are dead after the a2 frag loads; the quarter-size fp32 logits
// tile reuses their storage (wave-private, program-order safe). LDS 71 -> ~36 KB.
template<bool CB32>
__global__ __launch_bounds__(256) void k_encoder(const u16* __restrict__ wc,
                                                 const int* __restrict__ node_index,
                                                 const u16* __restrict__ wet,
                                                 const u16* __restrict__ w1t,
                                                 const u16* __restrict__ w2t,
                                                 u16* __restrict__ h_out, void* cb_out) {
    __shared__ alignas(16) u16 sH[4][16 * 136];   // 17.4 KB bf16 pre-gate h
    __shared__ alignas(16) char sScr[4][4608];    // 18.4 KB: zh(2304)+zl(2304) / myf(2304)
    __shared__ float sWo[64], sbo[8];
    int t = threadIdx.x;
    if (t < 64) sWo[t] = bf2f(wc[OFF_WO + t]);
    if (t < 8) sbo[t] = bf2f(wc[OFF_BO + t]);
    __syncthreads();

    int wave = t >> 6, lane = t & 63;
    int quad = lane >> 4, l15 = lane & 15;
    int base = blockIdx.x * 64 + wave * 16;
    int nodeA = base + l15; if (nodeA >= NN) nodeA = NN - 1;   // clamp reads; stores guarded

    uint4 afu = make_uint4(0u, 0u, 0u, 0u);
    if (quad == 0) {
        afu = ((const uint4*)(wc + OFF_TB))[node_index[nodeA]];
    } else if (quad == 1) {
        uint4 xv4 = ((const uint4*)(wc + OFF_X))[nodeA];
        float xv[8]; unpack8bf(xv4, xv);
        float o[8];
#pragma unroll
        for (int j = 0; j < 8; j++) {
            float a = sbo[j];
#pragma unroll
            for (int i = 0; i < 8; i++) a += xv[i] * sWo[i * 8 + j];
            o[j] = a;
        }
        afu = pack8bf(o);
    }
    bf16x8 af = __builtin_bit_cast(bf16x8, afu);

    f32x4 acch[8];
#pragma unroll
    for (int nt = 0; nt < 8; nt++) {
        float bv = bf2f(wc[OFF_BE + nt * 16 + l15]);
        f32x4 v; v[0] = bv; v[1] = bv; v[2] = bv; v[3] = bv;
        acch[nt] = v;
    }
#pragma unroll
    for (int nt = 0; nt < 8; nt++) {
        uint4 wb = ((const uint4*)(wet + (size_t)(nt * 16 + l15) * 32))[quad];
        bf16x8 bfrag = __builtin_bit_cast(bf16x8, wb);
        acch[nt] = __builtin_amdgcn_mfma_f32_16x16x32_bf16(af, bfrag, acch[nt], 0, 0, 0);
    }
    u16* hw = sH[wave];
#pragma unroll
    for (int nt = 0; nt < 8; nt++)
#pragma unroll
        for (int r = 0; r < 4; r++)
            hw[(quad * 4 + r) * 136 + nt * 16 + l15] = f2bf(acch[nt][r]);

    f32x4 acc1[4];
#pragma unroll
    for (int nt = 0; nt < 4; nt++) {
        float bv = bf2f(wc[OFF_LB1 + nt * 16 + l15]);
        f32x4 v; v[0] = bv; v[1] = bv; v[2] = bv; v[3] = bv;
        acc1[nt] = v;
    }
#pragma unroll
    for (int kc = 0; kc < 4; kc++) {
        bf16x8 a1 = __builtin_bit_cast(bf16x8,
                        *(const uint4*)(hw + l15 * 136 + kc * 32 + quad * 8));
#pragma unroll
        for (int nt = 0; nt < 4; nt++) {
            uint4 wb = ((const uint4*)(w1t + (size_t)(nt * 16 + l15) * FF))[kc * 4 + quad];
            bf16x8 bfrag = __builtin_bit_cast(bf16x8, wb);
            acc1[nt] = __builtin_amdgcn_mfma_f32_16x16x32_bf16(a1, bfrag, acc1[nt], 0, 0, 0);
        }
    }
    u16* zh = (u16*)sScr[wave];
    u16* zl = zh + 16 * 72;
#pragma unroll
    for (int nt = 0; nt < 4; nt++)
#pragma unroll
        for (int r = 0; r < 4; r++) {
            float v = acc1[nt][r];
            v = fmaxf(v, 0.2f * v);
            u16 hi16 = f2bf(v);
            float resid = v - bf2f(hi16);
            zh[(quad * 4 + r) * 72 + nt * 16 + l15] = hi16;
            zl[(quad * 4 + r) * 72 + nt * 16 + l15] = f2bf(resid);
        }
    bf16x8 a2h[2], a2l[2];
#pragma unroll
    for (int kc2 = 0; kc2 < 2; kc2++) {
        a2h[kc2] = __builtin_bit_cast(bf16x8,
                       *(const uint4*)(zh + l15 * 72 + kc2 * 32 + quad * 8));
        a2l[kc2] = __builtin_bit_cast(bf16x8,
                       *(const uint4*)(zl + l15 * 72 + kc2 * 32 + quad * 8));
    }
    f32x4 acc2[8];
#pragma unroll
    for (int nt = 0; nt < 8; nt++) {
        float bv = bf2f(wc[OFF_LB2 + nt * 16 + l15]);
        f32x4 v; v[0] = bv; v[1] = bv; v[2] = bv; v[3] = bv;
        acc2[nt] = v;
    }
#pragma unroll
    for (int kc2 = 0; kc2 < 2; kc2++)
#pragma unroll
        for (int nt = 0; nt < 8; nt++) {
            uint4 wb = ((const uint4*)(w2t + (size_t)(nt * 16 + l15) * HH))[kc2 * 4 + quad];
            bf16x8 bfrag = __builtin_bit_cast(bf16x8, wb);
            acc2[nt] = __builtin_amdgcn_mfma_f32_16x16x32_bf16(a2h[kc2], bfrag, acc2[nt], 0, 0, 0);
            acc2[nt] = __builtin_amdgcn_mfma_f32_16x16x32_bf16(a2l[kc2], bfrag, acc2[nt], 0, 0, 0);
        }
    // 4-pass epilogue: quarter logits tile (reuses zh/zl scratch; z frags consumed)
    float* myf = (float*)sScr[wave];
    int orow = lane >> 2, ocol = lane & 3;
    int onode = base + orow;
#pragma unroll
    for (int p = 0; p < 4; p++) {
#pragma unroll
        for (int h8 = 0; h8 < 2; h8++)
#pragma unroll
            for (int r = 0; r < 4; r++)
                myf[(quad * 4 + r) * 36 + h8 * 16 + l15] = acc2[2 * p + h8][r];
        if (onode < NN) {
            int k0 = p * 32 + ocol * 8;
            float f[8];
            unpack8bf(*(const uint4*)(hw + orow * 136 + k0), f);
            float4 lg1 = *(const float4*)(myf + orow * 36 + ocol * 8);
            float4 lg2 = *(const float4*)(myf + orow * 36 + ocol * 8 + 4);
            float lg[8] = {lg1.x, lg1.y, lg1.z, lg1.w, lg2.x, lg2.y, lg2.z, lg2.w};
            float ho[8], co[8];
#pragma unroll
            for (int j = 0; j < 8; j++) {
                float nw = 1.f / (1.f + __expf(-lg[j]));
                float hwv = f[j] * nw;
                ho[j] = hwv; co[j] = hwv * nw;
            }
            ((uint4*)(h_out + (size_t)onode * FF))[k0 / 8] = pack8bf(ho);
            cb_st<CB32>(cb_out, (size_t)onode, k0 / 4, make_float4(co[0], co[1], co[2], co[3]));
            cb_st<CB32>(cb_out, (size_t)onode, k0 / 4 + 1, make_float4(co[4], co[5], co[6], co[7]));
        }
    }
}

// ---------------- per-layer softmax aggregation (one CSR pass) ----------------
// 2 nodes per wave (R3 win). R7: 2-edge unrolled pipeline — paired s_src loads +
// back-to-back gathers double the outstanding loads per chain (latency-bound;
// identical per-edge op order and accumulation sequence).
__global__ __launch_bounds__(256) void k_agg(const u16* __restrict__ h,
                                             const int* __restrict__ row_ptr,
                                             const int* __restrict__ s_src,
                                             const u16* __restrict__ s_attr,
                                             const u16* __restrict__ wc, int layer,
                                             u16* __restrict__ agg) {
    int t = threadIdx.x;
    int hw = t >> 5, lane = t & 31;          // half-wave id (0..7), lane within half
    int node = blockIdx.x * 8 + hw;
    if (node >= NN) return;
    // lane owns u32 pairs {2*lane, 2*lane+1} = feats 4*lane .. 4*lane+3
    uint2 wcol[8];
#pragma unroll
    for (int k = 0; k < 8; k++) wcol[k] = ((const uint2*)(wc + OFF_WED))[k * 32 + lane];
    uint2 bcol = ((const uint2*)(wc + OFF_BED))[lane];
    float b0 = bflo(bcol.x), b1 = bfhi(bcol.x), b2 = bflo(bcol.y), b3 = bfhi(bcol.y);
    float tl = bf2f(wc[OFF_GT + layer]);
    int beg = row_ptr[node], end = row_ptr[node + 1];
    float n0 = 0.f, n1 = 0.f, n2 = 0.f, n3 = 0.f;
    float d0 = 0.f, d1 = 0.f, d2 = 0.f, d3 = 0.f;
    const uint2* h2 = (const uint2*)h;
    const uint4* at4 = (const uint4*)s_attr;
    auto edge = [&](uint4 av, uint2 hv) {
        float a[8]; unpack8bf(av, a);
        float e0 = b0, e1 = b1, e2 = b2, e3 = b3;
#pragma unroll
        for (int k = 0; k < 8; k++) {
            e0 += a[k] * bflo(wcol[k].x); e1 += a[k] * bfhi(wcol[k].x);
            e2 += a[k] * bflo(wcol[k].y); e3 += a[k] * bfhi(wcol[k].y);
        }
        float m0 = fmaxf(bflo(hv.x) + e0, 0.f) + 1e-7f;
        float m1 = fmaxf(bfhi(hv.x) + e1, 0.f) + 1e-7f;
        float m2 = fmaxf(bflo(hv.y) + e2, 0.f) + 1e-7f;
        float m3 = fmaxf(bfhi(hv.y) + e3, 0.f) + 1e-7f;
        float x0 = __expf(tl * m0), x1 = __expf(tl * m1);
        float x2 = __expf(tl * m2), x3 = __expf(tl * m3);
        n0 += x0 * m0; n1 += x1 * m1; n2 += x2 * m2; n3 += x3 * m3;
        d0 += x0; d1 += x1; d2 += x2; d3 += x3;
    };
    int i = beg;
    for (; i + 1 < end; i += 2) {
        int sid0 = s_src[i], sid1 = s_src[i + 1];
        uint2 hv0 = h2[(size_t)sid0 * 32 + lane];
        uint2 hv1 = h2[(size_t)sid1 * 32 + lane];
        uint4 av0 = at4[i], av1 = at4[i + 1];
        edge(av0, hv0);
        edge(av1, hv1);
    }
    if (i < end) {
        int sid = s_src[i];
        uint2 hv = h2[(size_t)sid * 32 + lane];
        edge(at4[i], hv);
    }
    uint2 r;
    r.x = pack2bf(n0 / (d0 + 1e-16f), n1 / (d1 + 1e-16f));
    r.y = pack2bf(n2 / (d2 + 1e-16f), n3 / (d3 + 1e-16f));
    ((uint2*)agg)[(size_t)node * 32 + lane] = r;
}

// ------- fused GCN MLP + LN + learner + highway (R5 fusion; R6 scratch union) -------
// R7: GEMM1's codebank slices prefetched into registers BEFORE the gcn MFMA
// phase — their ~500cy latency hides under 32 MFMAs + LDS + LN instead of
// sitting mid-chain. VGPR 72 -> ~104, still inside the 65-128 occupancy band
// (waves/SIMD quantum halves at 64/128/256 — m69).
template<bool CB32>
__global__ __launch_bounds__(256) void k_gcnpost(const u16* __restrict__ hb,  // agg (read)
                                                 u16* ha,       // h in / h_out (in place)
                                                 void* cbv,     // codebank r/w
                                                 const u16* __restrict__ wc,
                                                 const u16* __restrict__ wt,
                                                 const u16* __restrict__ w1t,
                                                 const u16* __restrict__ w2t, int layer) {
    __shared__ alignas(16) u16 sH1[4][16 * 136];   // 17.4 KB bf16 h1
    __shared__ alignas(16) char sScr[4][2304];     // 9.2 KB: zt / quarter-logits union
    __shared__ float smu[4][16], srstd[4][16];
    __shared__ float sg[FF], sbt[FF], sb1[HH], sb2[FF];
    int t = threadIdx.x;
    int ls = layer + 1;
    if (t < FF) {
        sg[t] = bf2f(wc[OFF_LG + layer * FF + t]);
        sbt[t] = bf2f(wc[OFF_LB + layer * FF + t]);
        sb2[t] = bf2f(wc[OFF_LB2 + ls * FF + t]);
    }
    if (t < HH) sb1[t] = bf2f(wc[OFF_LB1 + ls * HH + t]);
    __syncthreads();

    int wave = t >> 6, lane = t & 63;
    int quad = lane >> 4, l15 = lane & 15;
    int base = blockIdx.x * 64 + wave * 16;
    int nodeA = base + l15; if (nodeA >= NN) nodeA = NN - 1;   // clamp reads; stores guarded
    const u16* wtl = wt + (size_t)layer * FF * FF;
    const u16* w1l = w1t + (size_t)ls * HH * FF;   // [64][128]
    const u16* w2l = w2t + (size_t)ls * FF * HH;   // [128][64]

    // R7: prefetch GEMM1's cb slices (addresses depend only on nodeA). Clamped
    // lanes may race another wave's epilogue write of row NN-1 — their MFMA
    // output rows are discarded (same argument as the verified in-place k_gcn).
    float4 cbr0[4], cbr1[4];
#pragma unroll
    for (int kc = 0; kc < 4; kc++) {
        cbr0[kc] = cb_ld<CB32>(cbv, (size_t)nodeA, kc * 8 + quad * 2);
        cbr1[kc] = cb_ld<CB32>(cbv, (size_t)nodeA, kc * 8 + quad * 2 + 1);
    }

    // ---- gcn: h1 = (h + agg) @ gcn_W + gcn_b ----
    f32x4 accg[8];
#pragma unroll
    for (int nt = 0; nt < 8; nt++) {
        float bv = bf2f(wc[OFF_GB + layer * FF + nt * 16 + l15]);
        f32x4 v; v[0] = bv; v[1] = bv; v[2] = bv; v[3] = bv;
        accg[nt] = v;
    }
#pragma unroll
    for (int kc = 0; kc < 4; kc++) {
        uint4 hv = ((const uint4*)(ha + (size_t)nodeA * FF))[kc * 4 + quad];
        uint4 aa = ((const uint4*)(hb + (size_t)nodeA * FF))[kc * 4 + quad];
        float hf[8], af[8], sm[8];
        unpack8bf(hv, hf); unpack8bf(aa, af);
#pragma unroll
        for (int j = 0; j < 8; j++) sm[j] = hf[j] + af[j];
        uint4 pa = pack8bf(sm);
        bf16x8 afrag = __builtin_bit_cast(bf16x8, pa);
#pragma unroll
        for (int nt = 0; nt < 8; nt++) {
            uint4 wb = ((const uint4*)(wtl + (size_t)(nt * 16 + l15) * FF))[kc * 4 + quad];
            bf16x8 bfrag = __builtin_bit_cast(bf16x8, wb);
            accg[nt] = __builtin_amdgcn_mfma_f32_16x16x32_bf16(afrag, bfrag, accg[nt], 0, 0, 0);
        }
    }
    // h1 -> bf16 LDS tile (C layout -> row-major); wave-internal dep only
    u16* hw = sH1[wave];
#pragma unroll
    for (int nt = 0; nt < 8; nt++)
#pragma unroll
        for (int r = 0; r < 4; r++)
            hw[(quad * 4 + r) * 136 + nt * 16 + l15] = f2bf(accg[nt][r]);

    // ---- LN stats over own row l15 (read back from the tile) ----
    uint4 hreg[4];
    float s = 0.f, s2 = 0.f;
#pragma unroll
    for (int kc = 0; kc < 4; kc++) {
        hreg[kc] = *(const uint4*)(hw + l15 * 136 + kc * 32 + quad * 8);
        float f[8]; unpack8bf(hreg[kc], f);
#pragma unroll
        for (int j = 0; j < 8; j++) { s += f[j]; s2 += f[j] * f[j]; }
    }
    s += __shfl_xor(s, 16); s += __shfl_xor(s, 32);
    s2 += __shfl_xor(s2, 16); s2 += __shfl_xor(s2, 32);
    float mu = s * (1.f / 128.f);
    float var = fmaxf(s2 * (1.f / 128.f) - mu * mu, 0.f);
    float rstd = rsqrtf(var + 1e-5f);
    if (quad == 0) { smu[wave][l15] = mu; srstd[wave][l15] = rstd; }

    // ---- GEMM1 (K=128 -> 64 z), A = bf16(sv) + bf16(resid) ----
    f32x4 acc1[4];
#pragma unroll
    for (int nt = 0; nt < 4; nt++) {
        float bv = sb1[nt * 16 + l15];
        f32x4 v; v[0] = bv; v[1] = bv; v[2] = bv; v[3] = bv;
        acc1[nt] = v;
    }
#pragma unroll
    for (int kc = 0; kc < 4; kc++) {
        float f[8]; unpack8bf(hreg[kc], f);
        int k0 = kc * 32 + quad * 8;
        float4 ca = cbr0[kc];
        float4 cq = cbr1[kc];
        float cv[8] = {ca.x, ca.y, ca.z, ca.w, cq.x, cq.y, cq.z, cq.w};
        float sv[8];
#pragma unroll
        for (int j = 0; j < 8; j++) {
            float hl = fmaxf(sg[k0 + j] * (f[j] - mu) * rstd + sbt[k0 + j], 0.f);
            sv[j] = hl + cv[j];
        }
        uint4 ahi = pack8bf(sv);
        float thi[8]; unpack8bf(ahi, thi);
        float rv[8];
#pragma unroll
        for (int j = 0; j < 8; j++) rv[j] = sv[j] - thi[j];
        uint4 alo = pack8bf(rv);
        bf16x8 fhi = __builtin_bit_cast(bf16x8, ahi);
        bf16x8 flo = __builtin_bit_cast(bf16x8, alo);
#pragma unroll
        for (int nt = 0; nt < 4; nt++) {
            uint4 wb = ((const uint4*)(w1l + (size_t)(nt * 16 + l15) * FF))[kc * 4 + quad];
            bf16x8 bfrag = __builtin_bit_cast(bf16x8, wb);
            acc1[nt] = __builtin_amdgcn_mfma_f32_16x16x32_bf16(fhi, bfrag, acc1[nt], 0, 0, 0);
            acc1[nt] = __builtin_amdgcn_mfma_f32_16x16x32_bf16(flo, bfrag, acc1[nt], 0, 0, 0);
        }
    }
    // ---- leaky + z transpose via scratch (zt region) ----
    u16* ztw = (u16*)sScr[wave];
#pragma unroll
    for (int nt = 0; nt < 4; nt++)
#pragma unroll
        for (int r = 0; r < 4; r++) {
            float v = acc1[nt][r];
            v = fmaxf(v, 0.2f * v);
            ztw[(quad * 4 + r) * 72 + nt * 16 + l15] = f2bf(v);
        }
    bf16x8 a2[2];
#pragma unroll
    for (int kc2 = 0; kc2 < 2; kc2++)
        a2[kc2] = __builtin_bit_cast(bf16x8,
                      *(const uint4*)(ztw + l15 * 72 + kc2 * 32 + quad * 8));
    // ---- GEMM2 (K=64 -> 128), bf16 z ----
    f32x4 acc2[8];
#pragma unroll
    for (int nt = 0; nt < 8; nt++) {
        float bv = sb2[nt * 16 + l15];
        f32x4 v; v[0] = bv; v[1] = bv; v[2] = bv; v[3] = bv;
        acc2[nt] = v;
    }
#pragma unroll
    for (int kc2 = 0; kc2 < 2; kc2++)
#pragma unroll
        for (int nt = 0; nt < 8; nt++) {
            uint4 wb = ((const uint4*)(w2l + (size_t)(nt * 16 + l15) * HH))[kc2 * 4 + quad];
            bf16x8 bfrag = __builtin_bit_cast(bf16x8, wb);
            acc2[nt] = __builtin_amdgcn_mfma_f32_16x16x32_bf16(a2[kc2], bfrag, acc2[nt], 0, 0, 0);
        }
    // ---- 4-pass epilogue: quarter logits tile reuses the z scratch ----
    float* myf = (float*)sScr[wave];
    int orow = lane >> 2, ocol = lane & 3;
    int onode = base + orow;
#pragma unroll
    for (int p = 0; p < 4; p++) {
#pragma unroll
        for (int h8 = 0; h8 < 2; h8++)
#pragma unroll
            for (int r = 0; r < 4; r++)
                myf[(quad * 4 + r) * 36 + h8 * 16 + l15] = acc2[2 * p + h8][r];
        if (onode < NN) {
            float mu2 = smu[wave][orow], rstd2 = srstd[wave][orow];
            int k0 = p * 32 + ocol * 8;
            float f[8];
            unpack8bf(*(const uint4*)(hw + orow * 136 + k0), f);
            float4 lg1 = *(const float4*)(myf + orow * 36 + ocol * 8);
            float4 lg2 = *(const float4*)(myf + orow * 36 + ocol * 8 + 4);
            float lg[8] = {lg1.x, lg1.y, lg1.z, lg1.w, lg2.x, lg2.y, lg2.z, lg2.w};
            float4 ca = cb_ld<CB32>(cbv, (size_t)onode, k0 / 4);
            float4 cq = cb_ld<CB32>(cbv, (size_t)onode, k0 / 4 + 1);
            float cv[8] = {ca.x, ca.y, ca.z, ca.w, cq.x, cq.y, cq.z, cq.w};
            float ho[8], co[8];
#pragma unroll
            for (int j = 0; j < 8; j++) {
                float hl = fmaxf(sg[k0 + j] * (f[j] - mu2) * rstd2 + sbt[k0 + j], 0.f);
                float nw = 1.f / (1.f + __expf(-lg[j]));
                float hf = hl * nw;
                ho[j] = hf + cv[j] * (1.f - nw);
                co[j] = cv[j] + hf;
            }
            ((uint4*)(ha + (size_t)onode * FF))[k0 / 8] = pack8bf(ho);
            cb_st<CB32>(cbv, (size_t)onode, k0 / 4, make_float4(co[0], co[1], co[2], co[3]));
            cb_st<CB32>(cbv, (size_t)onode, k0 / 4 + 1, make_float4(co[4], co[5], co[6], co[7]));
        }
    }
}

// ------- prediction head via MFMA (R5, verified): cb read ONCE; hi/lo split for fp32 cb -------
template<bool CB32>
__global__ __launch_bounds__(256) void k_pred(const void* __restrict__ cbv,
                                              const u16* __restrict__ wc,
                                              const u16* __restrict__ wpt,
                                              const u32* __restrict__ gt_raw,
                                              void* __restrict__ outv) {
    __shared__ float sOutF[4][16 * 116];    // 29 KB fp32 logits (112 padded to 116)
    int t = threadIdx.x;
    int wave = t >> 6, lane = t & 63;
    int quad = lane >> 4, l15 = lane & 15;
    int base = blockIdx.x * 64 + wave * 16;
    int nodeA = base + l15; if (nodeA >= NN) nodeA = NN - 1;   // clamp reads; stores guarded
    bool f32o = is_f32(gt_raw);

    f32x4 acc[7];
#pragma unroll
    for (int nt = 0; nt < 7; nt++) {
        float bv = bf2f(wc[OFF_BP + nt * 16 + l15]);
        f32x4 v; v[0] = bv; v[1] = bv; v[2] = bv; v[3] = bv;
        acc[nt] = v;
    }
#pragma unroll
    for (int kc = 0; kc < 4; kc++) {
        float4 ca = cb_ld<CB32>(cbv, (size_t)nodeA, kc * 8 + quad * 2);
        float4 cq = cb_ld<CB32>(cbv, (size_t)nodeA, kc * 8 + quad * 2 + 1);
        float cv[8] = {ca.x, ca.y, ca.z, ca.w, cq.x, cq.y, cq.z, cq.w};
        uint4 ahi = pack8bf(cv);
        bf16x8 fhi = __builtin_bit_cast(bf16x8, ahi);
        bf16x8 flo;
        if (CB32) {
            float thi[8]; unpack8bf(ahi, thi);
            float rv[8];
#pragma unroll
            for (int j = 0; j < 8; j++) rv[j] = cv[j] - thi[j];
            flo = __builtin_bit_cast(bf16x8, pack8bf(rv));
        }
#pragma unroll
        for (int nt = 0; nt < 7; nt++) {
            uint4 wb = ((const uint4*)(wpt + (size_t)(nt * 16 + l15) * FF))[kc * 4 + quad];
            bf16x8 bfrag = __builtin_bit_cast(bf16x8, wb);
            acc[nt] = __builtin_amdgcn_mfma_f32_16x16x32_bf16(fhi, bfrag, acc[nt], 0, 0, 0);
            if (CB32)
                acc[nt] = __builtin_amdgcn_mfma_f32_16x16x32_bf16(flo, bfrag, acc[nt], 0, 0, 0);
        }
    }
    float* myf = sOutF[wave];
#pragma unroll
    for (int nt = 0; nt < 7; nt++)
#pragma unroll
        for (int r = 0; r < 4; r++)
            myf[(quad * 4 + r) * 116 + nt * 16 + l15] = acc[nt][r];
    // epilogue: 4 lanes/node, 28 feats/lane (wave-internal LDS dep)
    int orow = lane >> 2, ocol = lane & 3;
    int onode = base + orow;
    if (onode < NN) {
        if (f32o) {
            float4* o4 = (float4*)((float*)outv + (size_t)onode * TT + ocol * 28);
#pragma unroll
            for (int q = 0; q < 7; q++)
                o4[q] = *(const float4*)(myf + orow * 116 + ocol * 28 + q * 4);
        } else {
            uint2* o2 = (uint2*)((u16*)outv + (size_t)onode * TT + ocol * 28);
#pragma unroll
            for (int q = 0; q < 7; q++) {
                const float* p = myf + orow * 116 + ocol * 28 + q * 4;
                uint2 r; r.x = pack2bf(p[0], p[1]); r.y = pack2bf(p[2], p[3]);
                o2[q] = r;
            }
        }
    }
}

// ---------------------------------- launcher ----------------------------------
extern "C" void kernel_launch(void* const* d_in, const int* in_sizes, int n_in,
                              void* d_out, int out_size, void* d_ws, size_t ws_size,
                              hipStream_t stream) {
    const int* node_index = (const int*)d_in[1];
    const int* edge_index = (const int*)d_in[2];        // [2,E]: src then dst
    const u32* gt_raw = (const u32*)d_in[17];

    ConvPtrs ps;
    ps.p[0] = d_in[0];   // x
    ps.p[1] = d_in[4];   // table
    ps.p[2] = d_in[5];  ps.p[3] = d_in[6];   // W_ohe, b_ohe
    ps.p[4] = d_in[7];  ps.p[5] = d_in[8];   // W_enc, b_enc
    ps.p[6] = d_in[9];  ps.p[7] = d_in[10];  // W_edge, b_edge
    ps.p[8] = d_in[11]; ps.p[9] = d_in[12];  // lW1, lb1
    ps.p[10] = d_in[13]; ps.p[11] = d_in[14]; // lW2, lb2
    ps.p[12] = d_in[15]; ps.p[13] = d_in[16]; // gcn_W, gcn_b
    ps.p[14] = d_in[17];                      // gcn_t
    ps.p[15] = d_in[18]; ps.p[16] = d_in[19]; // ln_gamma, ln_beta
    ps.p[17] = d_in[20]; ps.p[18] = d_in[21]; // W_pred, b_pred

    auto pad = [](size_t b) { return (b + 255) & ~(size_t)255; };
    const size_t B_h = pad((size_t)NN * FF * 2);          // 25.6 MB bf16 node rows
    const size_t B_h1 = pad((size_t)(NN + 1) * FF * 2);   // +1 dummy row (legacy)
    const size_t B_cb32 = pad((size_t)(NN + 1) * FF * 4);
    const size_t B_cb16 = pad((size_t)(NN + 1) * FF * 2);
    const size_t B_attr = pad((size_t)EE * 8 * 2);        // 10 MB
    const size_t B_src = pad((size_t)EE * 4);             // 2.5 MB
    const size_t B_rp = pad((size_t)(NN + 1) * 4);
    const size_t B_cur = pad((size_t)NN * 4);
    const size_t B_bs = pad(256 * 4);
    const size_t B_wc = pad((size_t)CANON_N * 2);         // 5.27 MB
    const size_t B_wt = pad((size_t)LL * FF * FF * 2);    // 192 KB
    const size_t B_wlt = pad((size_t)7 * FF * HH * 2);    // 112 KB each (w1t, w2t)
    const size_t B_wet = pad((size_t)FF * 32 * 2);        // 8 KB padded W_enc^T
    const size_t B_wpt = pad((size_t)TT * FF * 2);        // 28 KB W_pred^T
    size_t fixed = B_h1 + B_h + B_attr + B_src + B_rp + B_cur + B_bs + B_wc + B_wt
                 + 2 * B_wlt + B_wet + B_wpt;
    bool cb32 = (fixed + B_cb32) <= ws_size;              // tier1 ~121 MB, tier2 ~95.7 MB

    char* w = (char*)d_ws;
    size_t off = 0;
    auto alloc = [&](size_t bytes) -> void* { void* p = w + off; off += bytes; return p; };
    u16* h_a = (u16*)alloc(B_h1);                         // h (+ dummy row NN)
    u16* hb = (u16*)alloc(B_h);                           // agg buffer
    void* cb = alloc(cb32 ? B_cb32 : B_cb16);             // codebank (+ dummy row NN)
    u16* s_attr = (u16*)alloc(B_attr);
    int* s_src = (int*)alloc(B_src);
    int* row_ptr = (int*)alloc(B_rp);
    int* cursor = (int*)alloc(B_cur);
    int* bsums = (int*)alloc(B_bs);
    u16* wc = (u16*)alloc(B_wc);
    u16* wt = (u16*)alloc(B_wt);
    u16* w1t = (u16*)alloc(B_wlt);
    u16* w2t = (u16*)alloc(B_wlt);
    u16* wet = (u16*)alloc(B_wet);
    u16* wpt = (u16*)alloc(B_wpt);

    const int GE = (EE + 255) / 256;     // 2442
    const int GA = (NN + 7) / 8;         // 12500 (2 nodes/wave, 8 nodes/block)
    const int GC = (CANON_N + 255) / 256;
    const int GG = (NN + 63) / 64;       // 1563  (MFMA kernels: 64 nodes/block)
    const int GT6 = (LL * FF * FF + 255) / 256;
    const int GTL = (2 * 7 * FF * HH + FF * 32 + TT * FF + 255) / 256;   // 520

    hipMemsetAsync(cursor, 0, (size_t)NN * 4, stream);
    k_convw<<<GC, 256, 0, stream>>>(ps, wc);
    k_twt<<<GT6, 256, 0, stream>>>(wc, wt);
    k_twl<<<GTL, 256, 0, stream>>>(wc, w1t, w2t, wet, wpt);
    k_hist<<<GE, 256, 0, stream>>>(edge_index + EE, cursor);
    k_scan1<<<SCAN_NB, 256, 0, stream>>>(cursor, bsums);
    k_scan2<<<1, 256, 0, stream>>>(bsums, row_ptr);
    k_scan3<<<SCAN_NB, 256, 0, stream>>>(cursor, row_ptr, bsums);
    k_scatter<<<GE, 256, 0, stream>>>(edge_index, edge_index + EE, d_in[3], gt_raw,
                                      cursor, s_src, s_attr);

    if (cb32) k_encoder<true><<<GG, 256, 0, stream>>>(wc, node_index, wet, w1t, w2t, h_a, cb);
    else      k_encoder<false><<<GG, 256, 0, stream>>>(wc, node_index, wet, w1t, w2t, h_a, cb);

    for (int l = 0; l < LL; l++) {
        k_agg<<<GA, 256, 0, stream>>>(h_a, row_ptr, s_src, s_attr, wc, l, hb);
        if (cb32) k_gcnpost<true><<<GG, 256, 0, stream>>>(hb, h_a, cb, wc, wt, w1t, w2t, l);
        else      k_gcnpost<false><<<GG, 256, 0, stream>>>(hb, h_a, cb, wc, wt, w1t, w2t, l);
    }
    if (cb32) k_pred<true><<<GG, 256, 0, stream>>>(cb, wc, wpt, gt_raw, d_out);
    else      k_pred<false><<<GG, 256, 0, stream>>>(cb, wc, wpt, gt_raw, d_out);
}

// Round 9
// 1234.938 us; speedup vs baseline: 1.0362x; 1.0362x over previous
//
#include <hip/hip_runtime.h>
#include <stdint.h>

#define NN 100000
#define EE 625000
#define FF 128
#define HH 64
#define LL 6
#define TT 112

#define SCAN_CHUNK 2048
#define SCAN_NB ((NN + SCAN_CHUNK - 1) / SCAN_CHUNK)   // 49

typedef unsigned short u16;
typedef unsigned int u32;
typedef __attribute__((ext_vector_type(8))) short bf16x8;
typedef __attribute__((ext_vector_type(4))) float f32x4;

// ---- canonical bf16 weight block layout (u16 element offsets, all 8-aligned) ----
#define OFF_X    0u          // 800000   x [N,8]
#define OFF_TB   800000u     // 1600000  table [200000,8]
#define OFF_WO   2400000u    // 64       W_ohe
#define OFF_BO   2400064u    // 8        b_ohe
#define OFF_WE   2400072u    // 2048     W_enc [16,128]
#define OFF_BE   2402120u    // 128      b_enc
#define OFF_WED  2402248u    // 1024     W_edge [8,128]
#define OFF_BED  2403272u    // 128      b_edge
#define OFF_LW1  2403400u    // 57344    learner_W1 [7,128,64]
#define OFF_LB1  2460744u    // 448      learner_b1 [7,64]
#define OFF_LW2  2461192u    // 57344    learner_W2 [7,64,128]
#define OFF_LB2  2518536u    // 896      learner_b2 [7,128]
#define OFF_GW   2519432u    // 98304    gcn_W [6,128,128]
#define OFF_GB   2617736u    // 768      gcn_b [6,128]
#define OFF_GT   2618504u    // 6 (slot padded to 8) gcn_t
#define OFF_LG   2618512u    // 768      ln_gamma [6,128]
#define OFF_LB   2619280u    // 768      ln_beta [6,128]
#define OFF_WP   2620048u    // 14336    W_pred [128,112]
#define OFF_BP   2634384u    // 112      b_pred
#define CANON_N  2634496u

// ---------- bf16 helpers (OCP bf16 = upper 16 bits of f32, RNE pack) ----------
__device__ __forceinline__ float bf2f(u16 u) { return __uint_as_float(((u32)u) << 16); }
__device__ __forceinline__ float bflo(u32 u) { return __uint_as_float(u << 16); }
__device__ __forceinline__ float bfhi(u32 u) { return __uint_as_float(u & 0xffff0000u); }
__device__ __forceinline__ u16 f2bf(float f) {
    u32 u = __float_as_uint(f);
    u32 r = u + 0x7fffu + ((u >> 16) & 1u);   // RNE
    return (u16)(r >> 16);
}
__device__ __forceinline__ u32 pack2bf(float lo, float hi) {
    return ((u32)f2bf(hi) << 16) | (u32)f2bf(lo);
}
__device__ __forceinline__ uint4 pack8bf(const float* f) {
    uint4 r;
    r.x = pack2bf(f[0], f[1]); r.y = pack2bf(f[2], f[3]);
    r.z = pack2bf(f[4], f[5]); r.w = pack2bf(f[6], f[7]);
    return r;
}
__device__ __forceinline__ void unpack8bf(uint4 u, float* f) {
    f[0] = bflo(u.x); f[1] = bfhi(u.x); f[2] = bflo(u.y); f[3] = bfhi(u.y);
    f[4] = bflo(u.z); f[5] = bfhi(u.z); f[6] = bflo(u.w); f[7] = bfhi(u.w);
}
// dtype flag: gcn_t = ones(6). fp32: word0 = 0x3F800000 (low16==0); bf16: 0x3F803F80.
__device__ __forceinline__ bool is_f32(const u32* gt_raw) {
    return (gt_raw[0] & 0xFFFFu) == 0u;
}

// ---------- codebank load/store: fp32 (tier1) or bf16 (tier2) ----------
template<bool CB32>
__device__ __forceinline__ float4 cb_ld(const void* cb, size_t row, int v) {
    if (CB32) {
        return ((const float4*)cb)[row * 32 + v];
    } else {
        uint2 u = ((const uint2*)cb)[row * 32 + v];
        float4 r; r.x = bflo(u.x); r.y = bfhi(u.x); r.z = bflo(u.y); r.w = bfhi(u.y);
        return r;
    }
}
template<bool CB32>
__device__ __forceinline__ void cb_st(void* cb, size_t row, int v, float4 val) {
    if (CB32) {
        ((float4*)cb)[row * 32 + v] = val;
    } else {
        uint2 u; u.x = pack2bf(val.x, val.y); u.y = pack2bf(val.z, val.w);
        ((uint2*)cb)[row * 32 + v] = u;
    }
}

// ---------------- input canonicalization: any float input -> bf16 block ----------------
struct ConvPtrs { const void* p[19]; };

__global__ __launch_bounds__(256) void k_convw(ConvPtrs ps, u16* __restrict__ wc) {
    u32 idx = blockIdx.x * 256 + threadIdx.x;
    if (idx >= CANON_N) return;
    const u32 offs[19] = {OFF_X, OFF_TB, OFF_WO, OFF_BO, OFF_WE, OFF_BE, OFF_WED, OFF_BED,
                          OFF_LW1, OFF_LB1, OFF_LW2, OFF_LB2, OFF_GW, OFF_GB, OFF_GT,
                          OFF_LG, OFF_LB, OFF_WP, OFF_BP};
    int seg = 0;
#pragma unroll
    for (int s = 1; s < 19; s++) if (idx >= offs[s]) seg = s;
    u32 e = idx - offs[seg];
    u16 v;
    if (seg == 14 && e >= 6u) {
        v = 0;                                   // gcn_t slot padding
    } else {
        bool f32 = is_f32((const u32*)ps.p[14]);
        v = f32 ? f2bf(((const float*)ps.p[seg])[e]) : ((const u16*)ps.p[seg])[e];
    }
    wc[idx] = v;
}

// gcn_W transpose: wt[l][f][k] = W[l][k][f]  (B-frag = contiguous 8 bf16 from W^T rows)
__global__ __launch_bounds__(256) void k_twt(const u16* __restrict__ wc, u16* __restrict__ wt) {
    int idx = blockIdx.x * 256 + threadIdx.x;
    if (idx >= LL * FF * FF) return;
    int l = idx >> 14, r = (idx >> 7) & 127, c = idx & 127;
    wt[idx] = wc[OFF_GW + l * FF * FF + c * FF + r];
}

// weight transposes for MFMA kernels:
// w1t[ls][n][k] = W1[ls][k][n]; w2t[ls][n][k] = W2[ls][k][n];
// wet[n][k] = W_enc[k][n] (k<16; zero-pad to 32); wpt[n][k] = W_pred[k][n];
// wedt[n][k] = W_edge[k][n] (k<8; zero-pad to 32)  [R8: for k_emb]
__global__ __launch_bounds__(256) void k_twl(const u16* __restrict__ wc,
                                             u16* __restrict__ w1t, u16* __restrict__ w2t,
                                             u16* __restrict__ wet, u16* __restrict__ wpt,
                                             u16* __restrict__ wedt) {
    int idx = blockIdx.x * 256 + threadIdx.x;
    const int HALF = 7 * FF * HH;                // 57344
    const int WETN = FF * 32;                    // 4096
    const int WPTN = TT * FF;                    // 14336
    if (idx < HALF) {
        int ls = idx / (FF * HH), rem = idx % (FF * HH);
        int n = rem / FF, k = rem % FF;          // w1t row n (64 rows), col k (128)
        w1t[idx] = wc[OFF_LW1 + ls * FF * HH + k * HH + n];
    } else if (idx < 2 * HALF) {
        int j = idx - HALF;
        int ls = j / (FF * HH), rem = j % (FF * HH);
        int n = rem / HH, k = rem % HH;          // w2t row n (128 rows), col k (64)
        w2t[j] = wc[OFF_LW2 + ls * FF * HH + k * FF + n];
    } else if (idx < 2 * HALF + WETN) {
        int j = idx - 2 * HALF;
        int n = j >> 5, k = j & 31;              // wet row n (128 rows), col k (32)
        wet[j] = (k < 16) ? wc[OFF_WE + k * FF + n] : (u16)0;
    } else if (idx < 2 * HALF + WETN + WPTN) {
        int j = idx - 2 * HALF - WETN;
        int n = j >> 7, k = j & 127;             // wpt row n (112 rows), col k (128)
        wpt[j] = wc[OFF_WP + k * TT + n];
    } else if (idx < 2 * HALF + WETN + WPTN + FF * 32) {
        int j = idx - 2 * HALF - WETN - WPTN;
        int n = j >> 5, k = j & 31;              // wedt row n (128 rows), col k (32)
        wedt[j] = (k < 8) ? wc[OFF_WED + k * FF + n] : (u16)0;
    }
}

// ---------------- CSR build: histogram -> scan -> scatter ----------------
__global__ void k_hist(const int* __restrict__ dst, int* __restrict__ counts) {
    int e = blockIdx.x * 256 + threadIdx.x;
    if (e < EE) atomicAdd(&counts[dst[e]], 1);
}

__global__ void k_scan1(const int* __restrict__ counts, int* __restrict__ bsums) {
    __shared__ int red[256];
    int t = threadIdx.x;
    int base = blockIdx.x * SCAN_CHUNK + t * 8;
    int s = 0;
#pragma unroll
    for (int j = 0; j < 8; j++) { int i = base + j; s += (i < NN) ? counts[i] : 0; }
    red[t] = s; __syncthreads();
    for (int off = 128; off > 0; off >>= 1) {
        if (t < off) red[t] += red[t + off];
        __syncthreads();
    }
    if (t == 0) bsums[blockIdx.x] = red[0];
}

__global__ void k_scan2(int* __restrict__ bsums, int* __restrict__ row_ptr) {
    __shared__ int v[256];
    int t = threadIdx.x;
    int x = (t < SCAN_NB) ? bsums[t] : 0;
    v[t] = x; __syncthreads();
    for (int off = 1; off < 256; off <<= 1) {
        int add = (t >= off) ? v[t - off] : 0;
        __syncthreads();
        v[t] += add;
        __syncthreads();
    }
    if (t < SCAN_NB) bsums[t] = v[t] - x;   // exclusive
    if (t == 0) row_ptr[NN] = EE;
}

__global__ void k_scan3(int* counts_cursor, int* __restrict__ row_ptr,
                        const int* __restrict__ bsums) {
    __shared__ int red[256];
    int t = threadIdx.x;
    int base = blockIdx.x * SCAN_CHUNK + t * 8;
    int c[8]; int s = 0;
#pragma unroll
    for (int j = 0; j < 8; j++) { int i = base + j; c[j] = (i < NN) ? counts_cursor[i] : 0; s += c[j]; }
    red[t] = s; __syncthreads();
    int own = s;
    for (int off = 1; off < 256; off <<= 1) {
        int add = (t >= off) ? red[t - off] : 0;
        __syncthreads();
        red[t] += add;
        __syncthreads();
    }
    int off0 = bsums[blockIdx.x] + red[t] - own;
    int run = 0;
#pragma unroll
    for (int j = 0; j < 8; j++) {
        int i = base + j;
        if (i < NN) { row_ptr[i] = off0 + run; counts_cursor[i] = off0 + run; }
        run += c[j];
    }
}

// scatter src id + edge_attr (converted to bf16) into CSR order
__global__ void k_scatter(const int* __restrict__ src, const int* __restrict__ dst,
                          const void* __restrict__ edge_attr, const u32* __restrict__ gt_raw,
                          int* __restrict__ cursor, int* __restrict__ s_src,
                          u16* __restrict__ s_attr) {
    int e = blockIdx.x * 256 + threadIdx.x;
    if (e >= EE) return;
    int d = dst[e];
    int p = atomicAdd(&cursor[d], 1);
    s_src[p] = src[e];
    if (is_f32(gt_raw)) {
        const float4* ea = (const float4*)edge_attr;
        float4 lo = ea[(size_t)e * 2], hi = ea[(size_t)e * 2 + 1];
        float f[8] = {lo.x, lo.y, lo.z, lo.w, hi.x, hi.y, hi.z, hi.w};
        ((uint4*)s_attr)[p] = pack8bf(f);
    } else {
        ((uint4*)s_attr)[p] = ((const uint4*)edge_attr)[e];
    }
}

// ------- R8: edge embedding precompute: emb[slot] = s_attr[slot]@W_edge + b_edge -------
// Layer-independent (matches reference structure: edge_emb computed once, outside
// the layer loop). MFMA nf-GEMM pattern (verified in k_encoder): quad0 A-frag =
// attr row, quads 1-3 zero; B = wedt [128][32] zero-padded. bf16 output, 160 MB.
__global__ __launch_bounds__(256) void k_emb(const u16* __restrict__ s_attr,
                                             const u16* __restrict__ wc,
                                             const u16* __restrict__ wedt,
                                             u16* __restrict__ emb) {
    __shared__ alignas(16) u16 sOut[4][16 * 136];
    int t = threadIdx.x;
    int wave = t >> 6, lane = t & 63;
    int quad = lane >> 4, l15 = lane & 15;
    long base = (long)blockIdx.x * 64 + wave * 16;
    long slotA = base + l15; if (slotA >= EE) slotA = EE - 1;   // clamp; stores guarded

    uint4 afu = make_uint4(0u, 0u, 0u, 0u);
    if (quad == 0) afu = ((const uint4*)s_attr)[slotA];
    bf16x8 af = __builtin_bit_cast(bf16x8, afu);

    f32x4 acc[8];
#pragma unroll
    for (int nt = 0; nt < 8; nt++) {
        float bv = bf2f(wc[OFF_BED + nt * 16 + l15]);
        f32x4 v; v[0] = bv; v[1] = bv; v[2] = bv; v[3] = bv;
        acc[nt] = v;
    }
#pragma unroll
    for (int nt = 0; nt < 8; nt++) {
        uint4 wb = ((const uint4*)(wedt + (size_t)(nt * 16 + l15) * 32))[quad];
        bf16x8 bfrag = __builtin_bit_cast(bf16x8, wb);
        acc[nt] = __builtin_amdgcn_mfma_f32_16x16x32_bf16(af, bfrag, acc[nt], 0, 0, 0);
    }
    u16* my = sOut[wave];
#pragma unroll
    for (int nt = 0; nt < 8; nt++)
#pragma unroll
        for (int r = 0; r < 4; r++)
            my[(quad * 4 + r) * 136 + nt * 16 + l15] = f2bf(acc[nt][r]);
    int orow = lane >> 2, ocol = lane & 3;
    long oslot = base + orow;
    if (oslot < EE) {
        uint4* dst = (uint4*)(emb + (size_t)oslot * FF);
        const uint4* srcl = (const uint4*)(my + orow * 136);
#pragma unroll
        for (int u = 0; u < 4; u++) dst[ocol * 4 + u] = srcl[ocol * 4 + u];
    }
}

// ---------------- per-layer softmax aggregation (one CSR pass) ----------------
// 2 nodes per wave (R3, verified). R8: k_agg was VALU-bound (81% VALUBusy) —
// the 32-FMA edge-embed recompute is 55% of per-edge ops and layer-invariant.
// EMB path reads the precomputed bf16 emb row instead (uint2/lane). Non-EMB
// path is the verified R3 recompute (workspace-tier fallback).
template<bool EMB>
__global__ __launch_bounds__(256) void k_agg(const u16* __restrict__ h,
                                             const int* __restrict__ row_ptr,
                                             const int* __restrict__ s_src,
                                             const u16* __restrict__ s_attr,
                                             const u16* __restrict__ emb,
                                             const u16* __restrict__ wc, int layer,
                                             u16* __restrict__ agg) {
    int t = threadIdx.x;
    int hw = t >> 5, lane = t & 31;          // half-wave id (0..7), lane within half
    int node = blockIdx.x * 8 + hw;
    if (node >= NN) return;
    float tl = bf2f(wc[OFF_GT + layer]);
    int beg = row_ptr[node], end = row_ptr[node + 1];
    float n0 = 0.f, n1 = 0.f, n2 = 0.f, n3 = 0.f;
    float d0 = 0.f, d1 = 0.f, d2 = 0.f, d3 = 0.f;
    const uint2* h2 = (const uint2*)h;
    if (EMB) {
        const uint2* e2 = (const uint2*)emb;
        for (int i = beg; i < end; i++) {
            int sid = s_src[i];
            uint2 hv = h2[(size_t)sid * 32 + lane];
            uint2 ev = e2[(size_t)i * 32 + lane];
            float e0 = bflo(ev.x), e1 = bfhi(ev.x), e2f = bflo(ev.y), e3 = bfhi(ev.y);
            float m0 = fmaxf(bflo(hv.x) + e0, 0.f) + 1e-7f;
            float m1 = fmaxf(bfhi(hv.x) + e1, 0.f) + 1e-7f;
            float m2 = fmaxf(bflo(hv.y) + e2f, 0.f) + 1e-7f;
            float m3 = fmaxf(bfhi(hv.y) + e3, 0.f) + 1e-7f;
            float x0 = __expf(tl * m0), x1 = __expf(tl * m1);
            float x2 = __expf(tl * m2), x3 = __expf(tl * m3);
            n0 += x0 * m0; n1 += x1 * m1; n2 += x2 * m2; n3 += x3 * m3;
            d0 += x0; d1 += x1; d2 += x2; d3 += x3;
        }
    } else {
        // lane owns u32 pairs {2*lane, 2*lane+1} = feats 4*lane .. 4*lane+3
        uint2 wcol[8];
#pragma unroll
        for (int k = 0; k < 8; k++) wcol[k] = ((const uint2*)(wc + OFF_WED))[k * 32 + lane];
        uint2 bcol = ((const uint2*)(wc + OFF_BED))[lane];
        float b0 = bflo(bcol.x), b1 = bfhi(bcol.x), b2 = bflo(bcol.y), b3 = bfhi(bcol.y);
        for (int i = beg; i < end; i++) {
            int sid = s_src[i];
            uint2 hv = h2[(size_t)sid * 32 + lane];
            uint4 av = ((const uint4*)s_attr)[i];    // half-wave-uniform address
            float a[8]; unpack8bf(av, a);
            float e0 = b0, e1 = b1, e2f = b2, e3 = b3;
#pragma unroll
            for (int k = 0; k < 8; k++) {
                e0 += a[k] * bflo(wcol[k].x); e1 += a[k] * bfhi(wcol[k].x);
                e2f += a[k] * bflo(wcol[k].y); e3 += a[k] * bfhi(wcol[k].y);
            }
            float m0 = fmaxf(bflo(hv.x) + e0, 0.f) + 1e-7f;
            float m1 = fmaxf(bfhi(hv.x) + e1, 0.f) + 1e-7f;
            float m2 = fmaxf(bflo(hv.y) + e2f, 0.f) + 1e-7f;
            float m3 = fmaxf(bfhi(hv.y) + e3, 0.f) + 1e-7f;
            float x0 = __expf(tl * m0), x1 = __expf(tl * m1);
            float x2 = __expf(tl * m2), x3 = __expf(tl * m3);
            n0 += x0 * m0; n1 += x1 * m1; n2 += x2 * m2; n3 += x3 * m3;
            d0 += x0; d1 += x1; d2 += x2; d3 += x3;
        }
    }
    uint2 r;
    r.x = pack2bf(n0 / (d0 + 1e-16f), n1 / (d1 + 1e-16f));
    r.y = pack2bf(n2 / (d2 + 1e-16f), n3 / (d3 + 1e-16f));
    ((uint2*)agg)[(size_t)node * 32 + lane] = r;
}

// ---------------- encoder via MFMA (R4 verified; R6: scratch union + 4-pass epilogue) ----------------
template<bool CB32>
__global__ __launch_bounds__(256) void k_encoder(const u16* __restrict__ wc,
                                                 const int* __restrict__ node_index,
                                                 const u16* __restrict__ wet,
                                                 const u16* __restrict__ w1t,
                                                 const u16* __restrict__ w2t,
                                                 u16* __restrict__ h_out, void* cb_out) {
    __shared__ alignas(16) u16 sH[4][16 * 136];   // 17.4 KB bf16 pre-gate h
    __shared__ alignas(16) char sScr[4][4608];    // 18.4 KB: zh(2304)+zl(2304) / myf(2304)
    __shared__ float sWo[64], sbo[8];
    int t = threadIdx.x;
    if (t < 64) sWo[t] = bf2f(wc[OFF_WO + t]);
    if (t < 8) sbo[t] = bf2f(wc[OFF_BO + t]);
    __syncthreads();

    int wave = t >> 6, lane = t & 63;
    int quad = lane >> 4, l15 = lane & 15;
    int base = blockIdx.x * 64 + wave * 16;
    int nodeA = base + l15; if (nodeA >= NN) nodeA = NN - 1;   // clamp reads; stores guarded

    uint4 afu = make_uint4(0u, 0u, 0u, 0u);
    if (quad == 0) {
        afu = ((const uint4*)(wc + OFF_TB))[node_index[nodeA]];
    } else if (quad == 1) {
        uint4 xv4 = ((const uint4*)(wc + OFF_X))[nodeA];
        float xv[8]; unpack8bf(xv4, xv);
        float o[8];
#pragma unroll
        for (int j = 0; j < 8; j++) {
            float a = sbo[j];
#pragma unroll
            for (int i = 0; i < 8; i++) a += xv[i] * sWo[i * 8 + j];
            o[j] = a;
        }
        afu = pack8bf(o);
    }
    bf16x8 af = __builtin_bit_cast(bf16x8, afu);

    f32x4 acch[8];
#pragma unroll
    for (int nt = 0; nt < 8; nt++) {
        float bv = bf2f(wc[OFF_BE + nt * 16 + l15]);
        f32x4 v; v[0] = bv; v[1] = bv; v[2] = bv; v[3] = bv;
        acch[nt] = v;
    }
#pragma unroll
    for (int nt = 0; nt < 8; nt++) {
        uint4 wb = ((const uint4*)(wet + (size_t)(nt * 16 + l15) * 32))[quad];
        bf16x8 bfrag = __builtin_bit_cast(bf16x8, wb);
        acch[nt] = __builtin_amdgcn_mfma_f32_16x16x32_bf16(af, bfrag, acch[nt], 0, 0, 0);
    }
    u16* hw = sH[wave];
#pragma unroll
    for (int nt = 0; nt < 8; nt++)
#pragma unroll
        for (int r = 0; r < 4; r++)
            hw[(quad * 4 + r) * 136 + nt * 16 + l15] = f2bf(acch[nt][r]);

    f32x4 acc1[4];
#pragma unroll
    for (int nt = 0; nt < 4; nt++) {
        float bv = bf2f(wc[OFF_LB1 + nt * 16 + l15]);
        f32x4 v; v[0] = bv; v[1] = bv; v[2] = bv; v[3] = bv;
        acc1[nt] = v;
    }
#pragma unroll
    for (int kc = 0; kc < 4; kc++) {
        bf16x8 a1 = __builtin_bit_cast(bf16x8,
                        *(const uint4*)(hw + l15 * 136 + kc * 32 + quad * 8));
#pragma unroll
        for (int nt = 0; nt < 4; nt++) {
            uint4 wb = ((const uint4*)(w1t + (size_t)(nt * 16 + l15) * FF))[kc * 4 + quad];
            bf16x8 bfrag = __builtin_bit_cast(bf16x8, wb);
            acc1[nt] = __builtin_amdgcn_mfma_f32_16x16x32_bf16(a1, bfrag, acc1[nt], 0, 0, 0);
        }
    }
    u16* zh = (u16*)sScr[wave];
    u16* zl = zh + 16 * 72;
#pragma unroll
    for (int nt = 0; nt < 4; nt++)
#pragma unroll
        for (int r = 0; r < 4; r++) {
            float v = acc1[nt][r];
            v = fmaxf(v, 0.2f * v);
            u16 hi16 = f2bf(v);
            float resid = v - bf2f(hi16);
            zh[(quad * 4 + r) * 72 + nt * 16 + l15] = hi16;
            zl[(quad * 4 + r) * 72 + nt * 16 + l15] = f2bf(resid);
        }
    bf16x8 a2h[2], a2l[2];
#pragma unroll
    for (int kc2 = 0; kc2 < 2; kc2++) {
        a2h[kc2] = __builtin_bit_cast(bf16x8,
                       *(const uint4*)(zh + l15 * 72 + kc2 * 32 + quad * 8));
        a2l[kc2] = __builtin_bit_cast(bf16x8,
                       *(const uint4*)(zl + l15 * 72 + kc2 * 32 + quad * 8));
    }
    f32x4 acc2[8];
#pragma unroll
    for (int nt = 0; nt < 8; nt++) {
        float bv = bf2f(wc[OFF_LB2 + nt * 16 + l15]);
        f32x4 v; v[0] = bv; v[1] = bv; v[2] = bv; v[3] = bv;
        acc2[nt] = v;
    }
#pragma unroll
    for (int kc2 = 0; kc2 < 2; kc2++)
#pragma unroll
        for (int nt = 0; nt < 8; nt++) {
            uint4 wb = ((const uint4*)(w2t + (size_t)(nt * 16 + l15) * HH))[kc2 * 4 + quad];
            bf16x8 bfrag = __builtin_bit_cast(bf16x8, wb);
            acc2[nt] = __builtin_amdgcn_mfma_f32_16x16x32_bf16(a2h[kc2], bfrag, acc2[nt], 0, 0, 0);
            acc2[nt] = __builtin_amdgcn_mfma_f32_16x16x32_bf16(a2l[kc2], bfrag, acc2[nt], 0, 0, 0);
        }
    // 4-pass epilogue: quarter logits tile (reuses zh/zl scratch; z frags consumed)
    float* myf = (float*)sScr[wave];
    int orow = lane >> 2, ocol = lane & 3;
    int onode = base + orow;
#pragma unroll
    for (int p = 0; p < 4; p++) {
#pragma unroll
        for (int h8 = 0; h8 < 2; h8++)
#pragma unroll
            for (int r = 0; r < 4; r++)
                myf[(quad * 4 + r) * 36 + h8 * 16 + l15] = acc2[2 * p + h8][r];
        if (onode < NN) {
            int k0 = p * 32 + ocol * 8;
            float f[8];
            unpack8bf(*(const uint4*)(hw + orow * 136 + k0), f);
            float4 lg1 = *(const float4*)(myf + orow * 36 + ocol * 8);
            float4 lg2 = *(const float4*)(myf + orow * 36 + ocol * 8 + 4);
            float lg[8] = {lg1.x, lg1.y, lg1.z, lg1.w, lg2.x, lg2.y, lg2.z, lg2.w};
            float ho[8], co[8];
#pragma unroll
            for (int j = 0; j < 8; j++) {
                float nw = 1.f / (1.f + __expf(-lg[j]));
                float hwv = f[j] * nw;
                ho[j] = hwv; co[j] = hwv * nw;
            }
            ((uint4*)(h_out + (size_t)onode * FF))[k0 / 8] = pack8bf(ho);
            cb_st<CB32>(cb_out, (size_t)onode, k0 / 4, make_float4(co[0], co[1], co[2], co[3]));
            cb_st<CB32>(cb_out, (size_t)onode, k0 / 4 + 1, make_float4(co[4], co[5], co[6], co[7]));
        }
    }
}

// ------- fused GCN MLP + LN + learner + highway (R5 fusion; R6 scratch union; R7 prefetch reverted) -------
template<bool CB32>
__global__ __launch_bounds__(256) void k_gcnpost(const u16* __restrict__ hb,  // agg (read)
                                                 u16* ha,       // h in / h_out (in place)
                                                 void* cbv,     // codebank r/w
                                                 const u16* __restrict__ wc,
                                                 const u16* __restrict__ wt,
                                                 const u16* __restrict__ w1t,
                                                 const u16* __restrict__ w2t, int layer) {
    __shared__ alignas(16) u16 sH1[4][16 * 136];   // 17.4 KB bf16 h1
    __shared__ alignas(16) char sScr[4][2304];     // 9.2 KB: zt / quarter-logits union
    __shared__ float smu[4][16], srstd[4][16];
    __shared__ float sg[FF], sbt[FF], sb1[HH], sb2[FF];
    int t = threadIdx.x;
    int ls = layer + 1;
    if (t < FF) {
        sg[t] = bf2f(wc[OFF_LG + layer * FF + t]);
        sbt[t] = bf2f(wc[OFF_LB + layer * FF + t]);
        sb2[t] = bf2f(wc[OFF_LB2 + ls * FF + t]);
    }
    if (t < HH) sb1[t] = bf2f(wc[OFF_LB1 + ls * HH + t]);
    __syncthreads();

    int wave = t >> 6, lane = t & 63;
    int quad = lane >> 4, l15 = lane & 15;
    int base = blockIdx.x * 64 + wave * 16;
    int nodeA = base + l15; if (nodeA >= NN) nodeA = NN - 1;   // clamp reads; stores guarded
    const u16* wtl = wt + (size_t)layer * FF * FF;
    const u16* w1l = w1t + (size_t)ls * HH * FF;   // [64][128]
    const u16* w2l = w2t + (size_t)ls * FF * HH;   // [128][64]

    // ---- gcn: h1 = (h + agg) @ gcn_W + gcn_b ----
    f32x4 accg[8];
#pragma unroll
    for (int nt = 0; nt < 8; nt++) {
        float bv = bf2f(wc[OFF_GB + layer * FF + nt * 16 + l15]);
        f32x4 v; v[0] = bv; v[1] = bv; v[2] = bv; v[3] = bv;
        accg[nt] = v;
    }
#pragma unroll
    for (int kc = 0; kc < 4; kc++) {
        uint4 hv = ((const uint4*)(ha + (size_t)nodeA * FF))[kc * 4 + quad];
        uint4 aa = ((const uint4*)(hb + (size_t)nodeA * FF))[kc * 4 + quad];
        float hf[8], af[8], sm[8];
        unpack8bf(hv, hf); unpack8bf(aa, af);
#pragma unroll
        for (int j = 0; j < 8; j++) sm[j] = hf[j] + af[j];
        uint4 pa = pack8bf(sm);
        bf16x8 afrag = __builtin_bit_cast(bf16x8, pa);
#pragma unroll
        for (int nt = 0; nt < 8; nt++) {
            uint4 wb = ((const uint4*)(wtl + (size_t)(nt * 16 + l15) * FF))[kc * 4 + quad];
            bf16x8 bfrag = __builtin_bit_cast(bf16x8, wb);
            accg[nt] = __builtin_amdgcn_mfma_f32_16x16x32_bf16(afrag, bfrag, accg[nt], 0, 0, 0);
        }
    }
    // h1 -> bf16 LDS tile (C layout -> row-major); wave-internal dep only
    u16* hw = sH1[wave];
#pragma unroll
    for (int nt = 0; nt < 8; nt++)
#pragma unroll
        for (int r = 0; r < 4; r++)
            hw[(quad * 4 + r) * 136 + nt * 16 + l15] = f2bf(accg[nt][r]);

    // ---- LN stats over own row l15 (read back from the tile) ----
    uint4 hreg[4];
    float s = 0.f, s2 = 0.f;
#pragma unroll
    for (int kc = 0; kc < 4; kc++) {
        hreg[kc] = *(const uint4*)(hw + l15 * 136 + kc * 32 + quad * 8);
        float f[8]; unpack8bf(hreg[kc], f);
#pragma unroll
        for (int j = 0; j < 8; j++) { s += f[j]; s2 += f[j] * f[j]; }
    }
    s += __shfl_xor(s, 16); s += __shfl_xor(s, 32);
    s2 += __shfl_xor(s2, 16); s2 += __shfl_xor(s2, 32);
    float mu = s * (1.f / 128.f);
    float var = fmaxf(s2 * (1.f / 128.f) - mu * mu, 0.f);
    float rstd = rsqrtf(var + 1e-5f);
    if (quad == 0) { smu[wave][l15] = mu; srstd[wave][l15] = rstd; }

    // ---- GEMM1 (K=128 -> 64 z), A = bf16(sv) + bf16(resid) ----
    f32x4 acc1[4];
#pragma unroll
    for (int nt = 0; nt < 4; nt++) {
        float bv = sb1[nt * 16 + l15];
        f32x4 v; v[0] = bv; v[1] = bv; v[2] = bv; v[3] = bv;
        acc1[nt] = v;
    }
#pragma unroll
    for (int kc = 0; kc < 4; kc++) {
        float f[8]; unpack8bf(hreg[kc], f);
        int k0 = kc * 32 + quad * 8;
        float4 ca = cb_ld<CB32>(cbv, (size_t)nodeA, kc * 8 + quad * 2);
        float4 cq = cb_ld<CB32>(cbv, (size_t)nodeA, kc * 8 + quad * 2 + 1);
        float cv[8] = {ca.x, ca.y, ca.z, ca.w, cq.x, cq.y, cq.z, cq.w};
        float sv[8];
#pragma unroll
        for (int j = 0; j < 8; j++) {
            float hl = fmaxf(sg[k0 + j] * (f[j] - mu) * rstd + sbt[k0 + j], 0.f);
            sv[j] = hl + cv[j];
        }
        uint4 ahi = pack8bf(sv);
        float thi[8]; unpack8bf(ahi, thi);
        float rv[8];
#pragma unroll
        for (int j = 0; j < 8; j++) rv[j] = sv[j] - thi[j];
        uint4 alo = pack8bf(rv);
        bf16x8 fhi = __builtin_bit_cast(bf16x8, ahi);
        bf16x8 flo = __builtin_bit_cast(bf16x8, alo);
#pragma unroll
        for (int nt = 0; nt < 4; nt++) {
            uint4 wb = ((const uint4*)(w1l + (size_t)(nt * 16 + l15) * FF))[kc * 4 + quad];
            bf16x8 bfrag = __builtin_bit_cast(bf16x8, wb);
            acc1[nt] = __builtin_amdgcn_mfma_f32_16x16x32_bf16(fhi, bfrag, acc1[nt], 0, 0, 0);
            acc1[nt] = __builtin_amdgcn_mfma_f32_16x16x32_bf16(flo, bfrag, acc1[nt], 0, 0, 0);
        }
    }
    // ---- leaky + z transpose via scratch (zt region) ----
    u16* ztw = (u16*)sScr[wave];
#pragma unroll
    for (int nt = 0; nt < 4; nt++)
#pragma unroll
        for (int r = 0; r < 4; r++) {
            float v = acc1[nt][r];
            v = fmaxf(v, 0.2f * v);
            ztw[(quad * 4 + r) * 72 + nt * 16 + l15] = f2bf(v);
        }
    bf16x8 a2[2];
#pragma unroll
    for (int kc2 = 0; kc2 < 2; kc2++)
        a2[kc2] = __builtin_bit_cast(bf16x8,
                      *(const uint4*)(ztw + l15 * 72 + kc2 * 32 + quad * 8));
    // ---- GEMM2 (K=64 -> 128), bf16 z ----
    f32x4 acc2[8];
#pragma unroll
    for (int nt = 0; nt < 8; nt++) {
        float bv = sb2[nt * 16 + l15];
        f32x4 v; v[0] = bv; v[1] = bv; v[2] = bv; v[3] = bv;
        acc2[nt] = v;
    }
#pragma unroll
    for (int kc2 = 0; kc2 < 2; kc2++)
#pragma unroll
        for (int nt = 0; nt < 8; nt++) {
            uint4 wb = ((const uint4*)(w2l + (size_t)(nt * 16 + l15) * HH))[kc2 * 4 + quad];
            bf16x8 bfrag = __builtin_bit_cast(bf16x8, wb);
            acc2[nt] = __builtin_amdgcn_mfma_f32_16x16x32_bf16(a2[kc2], bfrag, acc2[nt], 0, 0, 0);
        }
    // ---- 4-pass epilogue: quarter logits tile reuses the z scratch ----
    float* myf = (float*)sScr[wave];
    int orow = lane >> 2, ocol = lane & 3;
    int onode = base + orow;
#pragma unroll
    for (int p = 0; p < 4; p++) {
#pragma unroll
        for (int h8 = 0; h8 < 2; h8++)
#pragma unroll
            for (int r = 0; r < 4; r++)
                myf[(quad * 4 + r) * 36 + h8 * 16 + l15] = acc2[2 * p + h8][r];
        if (onode < NN) {
            float mu2 = smu[wave][orow], rstd2 = srstd[wave][orow];
            int k0 = p * 32 + ocol * 8;
            float f[8];
            unpack8bf(*(const uint4*)(hw + orow * 136 + k0), f);
            float4 lg1 = *(const float4*)(myf + orow * 36 + ocol * 8);
            float4 lg2 = *(const float4*)(myf + orow * 36 + ocol * 8 + 4);
            float lg[8] = {lg1.x, lg1.y, lg1.z, lg1.w, lg2.x, lg2.y, lg2.z, lg2.w};
            float4 ca = cb_ld<CB32>(cbv, (size_t)onode, k0 / 4);
            float4 cq = cb_ld<CB32>(cbv, (size_t)onode, k0 / 4 + 1);
            float cv[8] = {ca.x, ca.y, ca.z, ca.w, cq.x, cq.y, cq.z, cq.w};
            float ho[8], co[8];
#pragma unroll
            for (int j = 0; j < 8; j++) {
                float hl = fmaxf(sg[k0 + j] * (f[j] - mu2) * rstd2 + sbt[k0 + j], 0.f);
                float nw = 1.f / (1.f + __expf(-lg[j]));
                float hf = hl * nw;
                ho[j] = hf + cv[j] * (1.f - nw);
                co[j] = cv[j] + hf;
            }
            ((uint4*)(ha + (size_t)onode * FF))[k0 / 8] = pack8bf(ho);
            cb_st<CB32>(cbv, (size_t)onode, k0 / 4, make_float4(co[0], co[1], co[2], co[3]));
            cb_st<CB32>(cbv, (size_t)onode, k0 / 4 + 1, make_float4(co[4], co[5], co[6], co[7]));
        }
    }
}

// ------- prediction head via MFMA (R5, verified): cb read ONCE; hi/lo split for fp32 cb -------
template<bool CB32>
__global__ __launch_bounds__(256) void k_pred(const void* __restrict__ cbv,
                                              const u16* __restrict__ wc,
                                              const u16* __restrict__ wpt,
                                              const u32* __restrict__ gt_raw,
                                              void* __restrict__ outv) {
    __shared__ float sOutF[4][16 * 116];    // 29 KB fp32 logits (112 padded to 116)
    int t = threadIdx.x;
    int wave = t >> 6, lane = t & 63;
    int quad = lane >> 4, l15 = lane & 15;
    int base = blockIdx.x * 64 + wave * 16;
    int nodeA = base + l15; if (nodeA >= NN) nodeA = NN - 1;   // clamp reads; stores guarded
    bool f32o = is_f32(gt_raw);

    f32x4 acc[7];
#pragma unroll
    for (int nt = 0; nt < 7; nt++) {
        float bv = bf2f(wc[OFF_BP + nt * 16 + l15]);
        f32x4 v; v[0] = bv; v[1] = bv; v[2] = bv; v[3] = bv;
        acc[nt] = v;
    }
#pragma unroll
    for (int kc = 0; kc < 4; kc++) {
        float4 ca = cb_ld<CB32>(cbv, (size_t)nodeA, kc * 8 + quad * 2);
        float4 cq = cb_ld<CB32>(cbv, (size_t)nodeA, kc * 8 + quad * 2 + 1);
        float cv[8] = {ca.x, ca.y, ca.z, ca.w, cq.x, cq.y, cq.z, cq.w};
        uint4 ahi = pack8bf(cv);
        bf16x8 fhi = __builtin_bit_cast(bf16x8, ahi);
        bf16x8 flo;
        if (CB32) {
            float thi[8]; unpack8bf(ahi, thi);
            float rv[8];
#pragma unroll
            for (int j = 0; j < 8; j++) rv[j] = cv[j] - thi[j];
            flo = __builtin_bit_cast(bf16x8, pack8bf(rv));
        }
#pragma unroll
        for (int nt = 0; nt < 7; nt++) {
            uint4 wb = ((const uint4*)(wpt + (size_t)(nt * 16 + l15) * FF))[kc * 4 + quad];
            bf16x8 bfrag = __builtin_bit_cast(bf16x8, wb);
            acc[nt] = __builtin_amdgcn_mfma_f32_16x16x32_bf16(fhi, bfrag, acc[nt], 0, 0, 0);
            if (CB32)
                acc[nt] = __builtin_amdgcn_mfma_f32_16x16x32_bf16(flo, bfrag, acc[nt], 0, 0, 0);
        }
    }
    float* myf = sOutF[wave];
#pragma unroll
    for (int nt = 0; nt < 7; nt++)
#pragma unroll
        for (int r = 0; r < 4; r++)
            myf[(quad * 4 + r) * 116 + nt * 16 + l15] = acc[nt][r];
    // epilogue: 4 lanes/node, 28 feats/lane (wave-internal LDS dep)
    int orow = lane >> 2, ocol = lane & 3;
    int onode = base + orow;
    if (onode < NN) {
        if (f32o) {
            float4* o4 = (float4*)((float*)outv + (size_t)onode * TT + ocol * 28);
#pragma unroll
            for (int q = 0; q < 7; q++)
                o4[q] = *(const float4*)(myf + orow * 116 + ocol * 28 + q * 4);
        } else {
            uint2* o2 = (uint2*)((u16*)outv + (size_t)onode * TT + ocol * 28);
#pragma unroll
            for (int q = 0; q < 7; q++) {
                const float* p = myf + orow * 116 + ocol * 28 + q * 4;
                uint2 r; r.x = pack2bf(p[0], p[1]); r.y = pack2bf(p[2], p[3]);
                o2[q] = r;
            }
        }
    }
}

// ---------------------------------- launcher ----------------------------------
extern "C" void kernel_launch(void* const* d_in, const int* in_sizes, int n_in,
                              void* d_out, int out_size, void* d_ws, size_t ws_size,
                              hipStream_t stream) {
    const int* node_index = (const int*)d_in[1];
    const int* edge_index = (const int*)d_in[2];        // [2,E]: src then dst
    const u32* gt_raw = (const u32*)d_in[17];

    ConvPtrs ps;
    ps.p[0] = d_in[0];   // x
    ps.p[1] = d_in[4];   // table
    ps.p[2] = d_in[5];  ps.p[3] = d_in[6];   // W_ohe, b_ohe
    ps.p[4] = d_in[7];  ps.p[5] = d_in[8];   // W_enc, b_enc
    ps.p[6] = d_in[9];  ps.p[7] = d_in[10];  // W_edge, b_edge
    ps.p[8] = d_in[11]; ps.p[9] = d_in[12];  // lW1, lb1
    ps.p[10] = d_in[13]; ps.p[11] = d_in[14]; // lW2, lb2
    ps.p[12] = d_in[15]; ps.p[13] = d_in[16]; // gcn_W, gcn_b
    ps.p[14] = d_in[17];                      // gcn_t
    ps.p[15] = d_in[18]; ps.p[16] = d_in[19]; // ln_gamma, ln_beta
    ps.p[17] = d_in[20]; ps.p[18] = d_in[21]; // W_pred, b_pred

    auto pad = [](size_t b) { return (b + 255) & ~(size_t)255; };
    const size_t B_h = pad((size_t)NN * FF * 2);          // 25.6 MB bf16 node rows
    const size_t B_h1 = pad((size_t)(NN + 1) * FF * 2);   // +1 dummy row (legacy)
    const size_t B_cb32 = pad((size_t)(NN + 1) * FF * 4);
    const size_t B_cb16 = pad((size_t)(NN + 1) * FF * 2);
    const size_t B_attr = pad((size_t)EE * 8 * 2);        // 10 MB
    const size_t B_src = pad((size_t)EE * 4);             // 2.5 MB
    const size_t B_rp = pad((size_t)(NN + 1) * 4);
    const size_t B_cur = pad((size_t)NN * 4);
    const size_t B_bs = pad(256 * 4);
    const size_t B_wc = pad((size_t)CANON_N * 2);         // 5.27 MB
    const size_t B_wt = pad((size_t)LL * FF * FF * 2);    // 192 KB
    const size_t B_wlt = pad((size_t)7 * FF * HH * 2);    // 112 KB each (w1t, w2t)
    const size_t B_wet = pad((size_t)FF * 32 * 2);        // 8 KB padded W_enc^T
    const size_t B_wpt = pad((size_t)TT * FF * 2);        // 28 KB W_pred^T
    const size_t B_wedt = pad((size_t)FF * 32 * 2);       // 8 KB padded W_edge^T
    const size_t B_emb = pad((size_t)EE * FF * 2);        // 160 MB edge_emb (tiered)
    size_t fixed = B_h1 + B_h + B_attr + B_src + B_rp + B_cur + B_bs + B_wc + B_wt
                 + 2 * B_wlt + B_wet + B_wpt + B_wedt;
    bool cb32 = (fixed + B_cb32) <= ws_size;              // tier1 ~121 MB, tier2 ~95.7 MB
    size_t cbsz = cb32 ? B_cb32 : B_cb16;
    bool embok = (fixed + cbsz + B_emb) <= ws_size;       // tier0: +160 MB edge_emb

    char* w = (char*)d_ws;
    size_t off = 0;
    auto alloc = [&](size_t bytes) -> void* { void* p = w + off; off += bytes; return p; };
    u16* h_a = (u16*)alloc(B_h1);                         // h (+ dummy row NN)
    u16* hb = (u16*)alloc(B_h);                           // agg buffer
    void* cb = alloc(cbsz);                               // codebank (+ dummy row NN)
    u16* s_attr = (u16*)alloc(B_attr);
    int* s_src = (int*)alloc(B_src);
    int* row_ptr = (int*)alloc(B_rp);
    int* cursor = (int*)alloc(B_cur);
    int* bsums = (int*)alloc(B_bs);
    u16* wc = (u16*)alloc(B_wc);
    u16* wt = (u16*)alloc(B_wt);
    u16* w1t = (u16*)alloc(B_wlt);
    u16* w2t = (u16*)alloc(B_wlt);
    u16* wet = (u16*)alloc(B_wet);
    u16* wpt = (u16*)alloc(B_wpt);
    u16* wedt = (u16*)alloc(B_wedt);
    u16* s_emb = embok ? (u16*)alloc(B_emb) : nullptr;

    const int GE = (EE + 255) / 256;     // 2442
    const int GA = (NN + 7) / 8;         // 12500 (2 nodes/wave, 8 nodes/block)
    const int GC = (CANON_N + 255) / 256;
    const int GG = (NN + 63) / 64;       // 1563  (MFMA kernels: 64 nodes/block)
    const int GEM = (EE + 63) / 64;      // 9766  (k_emb: 64 slots/block)
    const int GT6 = (LL * FF * FF + 255) / 256;
    const int GTL = (2 * 7 * FF * HH + FF * 32 + TT * FF + FF * 32 + 255) / 256;   // 536

    hipMemsetAsync(cursor, 0, (size_t)NN * 4, stream);
    k_convw<<<GC, 256, 0, stream>>>(ps, wc);
    k_twt<<<GT6, 256, 0, stream>>>(wc, wt);
    k_twl<<<GTL, 256, 0, stream>>>(wc, w1t, w2t, wet, wpt, wedt);
    k_hist<<<GE, 256, 0, stream>>>(edge_index + EE, cursor);
    k_scan1<<<SCAN_NB, 256, 0, stream>>>(cursor, bsums);
    k_scan2<<<1, 256, 0, stream>>>(bsums, row_ptr);
    k_scan3<<<SCAN_NB, 256, 0, stream>>>(cursor, row_ptr, bsums);
    k_scatter<<<GE, 256, 0, stream>>>(edge_index, edge_index + EE, d_in[3], gt_raw,
                                      cursor, s_src, s_attr);
    if (embok) k_emb<<<GEM, 256, 0, stream>>>(s_attr, wc, wedt, s_emb);

    if (cb32) k_encoder<true><<<GG, 256, 0, stream>>>(wc, node_index, wet, w1t, w2t, h_a, cb);
    else      k_encoder<false><<<GG, 256, 0, stream>>>(wc, node_index, wet, w1t, w2t, h_a, cb);

    for (int l = 0; l < LL; l++) {
        if (embok)
            k_agg<true><<<GA, 256, 0, stream>>>(h_a, row_ptr, s_src, s_attr, s_emb, wc, l, hb);
        else
            k_agg<false><<<GA, 256, 0, stream>>>(h_a, row_ptr, s_src, s_attr, nullptr, wc, l, hb);
        if (cb32) k_gcnpost<true><<<GG, 256, 0, stream>>>(hb, h_a, cb, wc, wt, w1t, w2t, l);
        else      k_gcnpost<false><<<GG, 256, 0, stream>>>(hb, h_a, cb, wc, wt, w1t, w2t, l);
    }
    if (cb32) k_pred<true><<<GG, 256, 0, stream>>>(cb, wc, wpt, gt_raw, d_out);
    else      k_pred<false><<<GG, 256, 0, stream>>>(cb, wc, wpt, gt_raw, d_out);
}